// Round 11
// baseline (370.718 us; speedup 1.0000x reference)
//
#include <hip/hip_runtime.h>
#include <hip/hip_bf16.h>
#include <cstdint>

// ---------------------------------------------------------------------------
// GCN 3-layer forward, bf16 pipeline + MFMA GEMM + fp8 gather operand.
// R11: gather instruction diet. R10 showed fetch halved (88MB = 8-XCD floor)
//      but time only -8%: issue/latency-bound (VALUBusy 47%). Changes:
//      cvt_pk_f32_fp8 packed convert (1 instr / 2 cols), scalar row offset
//      via readfirstlane + hoisted per-lane base (kills 64-bit addr math),
//      ILP-8 load streams. Everything else identical to R10.
// ---------------------------------------------------------------------------

typedef unsigned short u16;
typedef unsigned int u32;
typedef unsigned char u8;
typedef __attribute__((ext_vector_type(8))) short short8v;
typedef __attribute__((ext_vector_type(4))) float f32x4;
typedef __attribute__((ext_vector_type(2))) float f32x2;

#define NBMAX 256
#define BKSH  9
#define SCH   2048

__device__ inline u16 f2bf(float f) {
  u32 u = __float_as_uint(f);
  u += 0x7fff + ((u >> 16) & 1);  // RNE
  return (u16)(u >> 16);
}
__device__ inline float bflo(u32 u) { return __uint_as_float(u << 16); }
__device__ inline float bfhi(u32 u) { return __uint_as_float(u & 0xffff0000u); }

// --- init: block 0 detects edge dtype, block 1 zeros counters ---------------
__global__ void k_init(const int* __restrict__ ei, int* __restrict__ mode,
                       int* __restrict__ bucketCnt, float* __restrict__ pooled,
                       int e, int nb) {
  if (blockIdx.x == 0) {
    __shared__ int any;
    if (threadIdx.x == 0) any = 0;
    __syncthreads();
    int lim = min(e, 2048);
    int local = 0;
    for (int i = threadIdx.x; i < lim; i += blockDim.x)
      local |= (ei[2 * i + 1] != 0);
    if (local) atomicOr(&any, 1);
    __syncthreads();
    if (threadIdx.x == 0) mode[0] = (any == 0) ? 1 : 0;
  } else {
    int i = threadIdx.x;
    if (i < nb) bucketCnt[i] = 0;
    if (i < 128) pooled[i] = 0.0f;
  }
}

// --- CSR build: 2-level radix by destination --------------------------------
__global__ __launch_bounds__(256) void b_count(const int* __restrict__ ei,
                                               const int* __restrict__ mode,
                                               int* __restrict__ bucketCnt,
                                               int e, int nb) {
  __shared__ int lh[NBMAX];
  int t = threadIdx.x;
  lh[t] = 0;
  __syncthreads();
  int m = mode[0];
  int stride = gridDim.x * 256;
  for (int i = blockIdx.x * 256 + t; i < e; i += stride) {
    long long di = (long long)e + i;
    int d = m ? ei[2 * di] : ei[di];
    atomicAdd(&lh[d >> BKSH], 1);
  }
  __syncthreads();
  if (t < nb && lh[t]) atomicAdd(&bucketCnt[t], lh[t]);
}

__global__ __launch_bounds__(256) void b_bscan(const int* __restrict__ bucketCnt,
                                               int* __restrict__ bucketOff,
                                               int* __restrict__ bucketCur,
                                               int nb, int e) {
  __shared__ int sh[NBMAX];
  int t = threadIdx.x;
  int c = (t < nb) ? bucketCnt[t] : 0;
  sh[t] = c;
  __syncthreads();
  for (int d = 1; d < NBMAX; d <<= 1) {
    int v = (t >= d) ? sh[t - d] : 0;
    __syncthreads();
    sh[t] += v;
    __syncthreads();
  }
  int ex = sh[t] - c;
  if (t < nb) { bucketOff[t] = ex; bucketCur[t] = ex; }
  if (t == 0) bucketOff[nb] = e;
}

__global__ __launch_bounds__(256) void b_scatter(const int* __restrict__ ei,
                                                 const int* __restrict__ mode,
                                                 int* __restrict__ bucketCur,
                                                 int* __restrict__ pairBuf,
                                                 int e, int nb) {
  __shared__ int cnt[NBMAX];
  __shared__ int pre[NBMAX];
  __shared__ int base[NBMAX];
  __shared__ int stage[2 * SCH];
  const int t = threadIdx.x;
  const int chunk0 = blockIdx.x * SCH;
  const int nloc = min(SCH, e - chunk0);
  const int m = mode[0];

  cnt[t] = 0;
  __syncthreads();

  int myS[SCH / 256], myD[SCH / 256], myB[SCH / 256], mySlot[SCH / 256];
#pragma unroll
  for (int j = 0; j < SCH / 256; ++j) {
    int li = j * 256 + t;
    myB[j] = -1;
    if (li < nloc) {
      int i = chunk0 + li;
      long long di = (long long)e + i;
      int s = m ? ei[2 * (long long)i] : ei[i];
      int d = m ? ei[2 * di] : ei[di];
      int b = d >> BKSH;
      myS[j] = s; myD[j] = d; myB[j] = b;
      mySlot[j] = atomicAdd(&cnt[b], 1);
    }
  }
  __syncthreads();

  int c0 = cnt[t];
  pre[t] = c0;
  __syncthreads();
  for (int d = 1; d < NBMAX; d <<= 1) {
    int v = (t >= d) ? pre[t - d] : 0;
    __syncthreads();
    pre[t] += v;
    __syncthreads();
  }
  int myPre = pre[t] - c0;
  if (t < nb && c0 > 0) base[t] = atomicAdd(&bucketCur[t], c0);
  __syncthreads();
  cnt[t] = myPre;
  __syncthreads();

#pragma unroll
  for (int j = 0; j < SCH / 256; ++j) {
    if (myB[j] >= 0) {
      int si = cnt[myB[j]] + mySlot[j];
      stage[2 * si] = myS[j];
      stage[2 * si + 1] = myD[j];
    }
  }
  __syncthreads();

  int wave = t >> 6, lane = t & 63;
  for (int b = wave; b < nb; b += 4) {
    int cb = pre[b] - cnt[b];
    if (cb <= 0) continue;
    int lo = cnt[b];
    size_t gb = (size_t)base[b];
    for (int j = lane; j < 2 * cb; j += 64)
      pairBuf[2 * gb + j] = stage[2 * lo + j];
  }
}

__global__ __launch_bounds__(512) void b_fine(const int* __restrict__ pairBuf,
                                              const int* __restrict__ bucketOff,
                                              int* __restrict__ offs,
                                              float* __restrict__ dis,
                                              int* __restrict__ csr,
                                              int n, int e) {
  const int b = blockIdx.x;
  const int d0 = b << BKSH;
  const int lo = bucketOff[b], hi = bucketOff[b + 1];
  __shared__ int arr[1 << BKSH];
  __shared__ int cur[1 << BKSH];
  const int t = threadIdx.x;
  arr[t] = 0; cur[t] = 0;
  __syncthreads();
  for (int i = lo + t; i < hi; i += 512) {
    int d = pairBuf[2 * (size_t)i + 1];
    atomicAdd(&arr[d - d0], 1);
  }
  __syncthreads();
  int c0 = arr[t];
  __syncthreads();
  for (int dd = 1; dd < 512; dd <<= 1) {
    int v = (t >= dd) ? arr[t - dd] : 0;
    __syncthreads();
    arr[t] += v;
    __syncthreads();
  }
  int epre = arr[t] - c0;
  int gd = d0 + t;
  if (gd < n) {
    offs[gd] = lo + epre;
    dis[gd] = rsqrtf((float)c0 + 1.0f);
  }
  __syncthreads();
  arr[t] = epre;
  __syncthreads();
  for (int i = lo + t; i < hi; i += 512) {
    int s = pairBuf[2 * (size_t)i];
    int d = pairBuf[2 * (size_t)i + 1];
    int ld = d - d0;
    int p = lo + arr[ld] + atomicAdd(&cur[ld], 1);
    csr[p] = s;
  }
  if (b == 0 && t == 0) offs[n] = e;
}

// --- pack all 3 weights fp32 -> MFMA B-fragments bf16 (grid 24) -------------
__global__ __launch_bounds__(256) void k_wpack3(const float* __restrict__ W0,
                                                const float* __restrict__ W1,
                                                const float* __restrict__ W2,
                                                u16* __restrict__ wp) {
  int f = blockIdx.x * 256 + threadIdx.x;
  int wsel = f >> 11;
  int li = f & 2047;
  const float* W = (wsel == 0) ? W0 : (wsel == 1) ? W1 : W2;
  u16* dst = wp + (size_t)wsel * 2048 * 8;
  int ct = li >> 8, kc = (li >> 6) & 3, lane = li & 63;
  int g = lane >> 4, c = lane & 15;
  u32 o[4];
#pragma unroll
  for (int q = 0; q < 4; ++q) {
    int k = kc * 32 + g * 8 + q * 2;
    u16 e0 = f2bf(W[(size_t)k * 128 + ct * 16 + c]);
    u16 e1 = f2bf(W[(size_t)(k + 1) * 128 + ct * 16 + c]);
    o[q] = (u32)e0 | ((u32)e1 << 16);
  }
  uint4 v; v.x = o[0]; v.y = o[1]; v.z = o[2]; v.w = o[3];
  *reinterpret_cast<uint4*>(dst + (size_t)li * 8) = v;
}

// --- GEMM: tmp[r,:] = fp8( 16 * dis[r] * (h[r,:] @ W) ) via MFMA ------------
template <bool FP32IN>
__global__ __launch_bounds__(256) void k_gemm_mfma(const void* __restrict__ hin,
                                                   const u16* __restrict__ wp,
                                                   const float* __restrict__ dis,
                                                   u8* __restrict__ tmpf8, int n) {
  __shared__ float eps[64 * 132];
  const int tid = threadIdx.x;
  const int w = tid >> 6, l = tid & 63;
  const int g = l >> 4, c16 = l & 15;
  const int rowbase = blockIdx.x * 64 + w * 16;

  const short8v zero8 = {0, 0, 0, 0, 0, 0, 0, 0};
  short8v a[4];
  int ar = rowbase + c16;
  bool aok = ar < n;
#pragma unroll
  for (int kc = 0; kc < 4; ++kc) {
    if (FP32IN) {
      const float* hrow = (const float*)hin + (size_t)ar * 128;
      short8v s = zero8;
      if (aok) {
        float4 v0 = *reinterpret_cast<const float4*>(hrow + kc * 32 + g * 8);
        float4 v1 = *reinterpret_cast<const float4*>(hrow + kc * 32 + g * 8 + 4);
        s[0] = (short)f2bf(v0.x); s[1] = (short)f2bf(v0.y);
        s[2] = (short)f2bf(v0.z); s[3] = (short)f2bf(v0.w);
        s[4] = (short)f2bf(v1.x); s[5] = (short)f2bf(v1.y);
        s[6] = (short)f2bf(v1.z); s[7] = (short)f2bf(v1.w);
      }
      a[kc] = s;
    } else {
      const u16* hrow = (const u16*)hin + (size_t)ar * 128;
      a[kc] = aok ? *reinterpret_cast<const short8v*>(hrow + kc * 32 + g * 8) : zero8;
    }
  }

  f32x4 acc[8];
#pragma unroll
  for (int ct = 0; ct < 8; ++ct) acc[ct] = f32x4{0.f, 0.f, 0.f, 0.f};

#pragma unroll
  for (int ct = 0; ct < 8; ++ct) {
#pragma unroll
    for (int kc = 0; kc < 4; ++kc) {
      short8v b = *reinterpret_cast<const short8v*>(wp + ((size_t)(ct * 4 + kc) * 64 + l) * 8);
      acc[ct] = __builtin_amdgcn_mfma_f32_16x16x32_bf16(a[kc], b, acc[ct], 0, 0, 0);
    }
  }

  // scale by 16*dis[row] (x16 clears fp8 subnormal region; gather divides out)
#pragma unroll
  for (int j = 0; j < 4; ++j) {
    int rl = w * 16 + g * 4 + j;
    int gr = blockIdx.x * 64 + rl;
    float dn = (gr < n) ? dis[gr] * 16.0f : 0.f;
#pragma unroll
    for (int ct = 0; ct < 8; ++ct)
      eps[rl * 132 + ct * 16 + c16] = acc[ct][j] * dn;
  }
  __syncthreads();

  // readback: thread -> (row rl, 32-col segment), pack fp8 and store 32B
  int rl = tid >> 2, seg = tid & 3;
  int gr = blockIdx.x * 64 + rl;
  if (gr < n) {
    const float* src = &eps[rl * 132 + seg * 32];
    u32 wds[8];
#pragma unroll
    for (int q = 0; q < 4; ++q) {
      float4 v0 = *reinterpret_cast<const float4*>(src + q * 8);
      float4 v1 = *reinterpret_cast<const float4*>(src + q * 8 + 4);
      int p0 = __builtin_amdgcn_cvt_pk_fp8_f32(v0.x, v0.y, 0, false);
      p0 = __builtin_amdgcn_cvt_pk_fp8_f32(v0.z, v0.w, p0, true);
      int p1 = __builtin_amdgcn_cvt_pk_fp8_f32(v1.x, v1.y, 0, false);
      p1 = __builtin_amdgcn_cvt_pk_fp8_f32(v1.z, v1.w, p1, true);
      wds[q * 2] = (u32)p0;
      wds[q * 2 + 1] = (u32)p1;
    }
    uint4 o0; o0.x = wds[0]; o0.y = wds[1]; o0.z = wds[2]; o0.w = wds[3];
    uint4 o1; o1.x = wds[4]; o1.y = wds[5]; o1.z = wds[6]; o1.w = wds[7];
    *reinterpret_cast<uint4*>(tmpf8 + (size_t)gr * 128 + seg * 32) = o0;
    *reinterpret_cast<uint4*>(tmpf8 + (size_t)gr * 128 + seg * 32 + 16) = o1;
  }
}

// --- gather: one wave per node, u16 (2 fp8 cols) per lane, ILP-8 ------------
// scalar row offsets (readfirstlane) + hoisted per-lane base + packed cvt.
__global__ __launch_bounds__(256) void k_gather_f8(const u8* __restrict__ tmpf8,
                                                   const int* __restrict__ csr,
                                                   const int* __restrict__ offs,
                                                   const float* __restrict__ dis,
                                                   const float* __restrict__ bias,
                                                   u16* __restrict__ houtb, int n) {
  int node = blockIdx.x * 4 + (threadIdx.x >> 6);
  if (node >= n) return;
  int lane = threadIdx.x & 63;
  const u16* tp = reinterpret_cast<const u16*>(tmpf8) + lane;  // per-lane base
  int s0 = offs[node], s1 = offs[node + 1];

  f32x2 acc[8];
#pragma unroll
  for (int i = 0; i < 8; ++i) acc[i] = f32x2{0.f, 0.f};

  int e = s0;
  for (; e + 7 < s1; e += 8) {
    int ro[8];
#pragma unroll
    for (int j = 0; j < 8; ++j)
      ro[j] = __builtin_amdgcn_readfirstlane(csr[e + j]) << 6;  // u16 elems
    u32 v[8];
#pragma unroll
    for (int j = 0; j < 8; ++j) v[j] = tp[(u32)ro[j]];
#pragma unroll
    for (int j = 0; j < 8; ++j)
      acc[j] += __builtin_amdgcn_cvt_pk_f32_fp8((int)v[j], false);
  }
  for (; e < s1; ++e) {
    int r = __builtin_amdgcn_readfirstlane(csr[e]) << 6;
    acc[0] += __builtin_amdgcn_cvt_pk_f32_fp8((int)tp[(u32)r], false);
  }
  // self-loop row
  acc[1] += __builtin_amdgcn_cvt_pk_f32_fp8((int)tp[(u32)node << 6], false);

  f32x2 t0 = (acc[0] + acc[1]) + (acc[2] + acc[3]);
  f32x2 t1 = (acc[4] + acc[5]) + (acc[6] + acc[7]);
  f32x2 s = t0 + t1;

  float dn = dis[node] * 0.0625f;  // /16 undoes the fp8 pre-scale
  float2 bb = reinterpret_cast<const float2*>(bias)[lane];
  float rx = fmaf(dn, s.x, bb.x);
  float ry = fmaf(dn, s.y, bb.y);
  rx = rx > 0.f ? rx : 0.f;
  ry = ry > 0.f ? ry : 0.f;
  u32 o = (u32)f2bf(rx) | ((u32)f2bf(ry) << 16);
  reinterpret_cast<u32*>(houtb)[(size_t)node * 64 + lane] = o;
}

// --- mean-pool column sums (bf16 in, fp32 out); 512 blocks -> 65K atomics ---
__global__ __launch_bounds__(256) void k_pool_bf(const u16* __restrict__ h,
                                                 float* __restrict__ pooled, int n) {
  int lane = threadIdx.x & 63, wv = threadIdx.x >> 6;
  const u32* hp = reinterpret_cast<const u32*>(h);
  float sx = 0.f, sy = 0.f;
  for (int r = blockIdx.x * 4 + wv; r < n; r += gridDim.x * 4) {
    u32 u = hp[(size_t)r * 64 + lane];
    sx += bflo(u); sy += bfhi(u);
  }
  __shared__ float red[2][256];
  red[0][threadIdx.x] = sx;
  red[1][threadIdx.x] = sy;
  __syncthreads();
  if (threadIdx.x < 64) {
    float tx = red[0][threadIdx.x] + red[0][threadIdx.x + 64] +
               red[0][threadIdx.x + 128] + red[0][threadIdx.x + 192];
    float ty = red[1][threadIdx.x] + red[1][threadIdx.x + 64] +
               red[1][threadIdx.x + 128] + red[1][threadIdx.x + 192];
    atomicAdd(&pooled[threadIdx.x * 2], tx);
    atomicAdd(&pooled[threadIdx.x * 2 + 1], ty);
  }
}

__global__ void k_final(const float* __restrict__ pooled, const float* __restrict__ Wfc,
                        const float* __restrict__ bfc, float* __restrict__ out,
                        float invn) {
  int j = threadIdx.x;
  if (j < 32) {
    float acc = 0.f;
    for (int k = 0; k < 128; ++k) acc = fmaf(pooled[k], Wfc[k * 32 + j], acc);
    out[j] = fmaf(acc, invn, bfc[j]);
  }
}

extern "C" void kernel_launch(void* const* d_in, const int* in_sizes, int n_in,
                              void* d_out, int out_size, void* d_ws, size_t ws_size,
                              hipStream_t stream) {
  const float* x   = (const float*)d_in[0];
  const int*   ei  = (const int*)d_in[1];
  const float* W0  = (const float*)d_in[2];
  const float* b0  = (const float*)d_in[3];
  const float* W1  = (const float*)d_in[4];
  const float* b1  = (const float*)d_in[5];
  const float* W2  = (const float*)d_in[6];
  const float* b2  = (const float*)d_in[7];
  const float* Wfc = (const float*)d_in[8];
  const float* bfc = (const float*)d_in[9];

  const int n = in_sizes[0] / 128;
  const int e = in_sizes[1] / 2;
  const int nb = (n + (1 << BKSH) - 1) >> BKSH;

  char* ws = (char*)d_ws;
  size_t off = 0;
  auto alloc = [&](size_t bytes) -> void* {
    void* p = ws + off;
    off = (off + bytes + 255) & ~(size_t)255;
    return p;
  };
  int*   mode      = (int*)alloc(sizeof(int));
  int*   bucketCnt = (int*)alloc(NBMAX * 4);
  int*   bucketOff = (int*)alloc((NBMAX + 1) * 4);
  int*   bucketCur = (int*)alloc(NBMAX * 4);
  int*   offs      = (int*)alloc((size_t)(n + 1) * 4);
  float* dis       = (float*)alloc((size_t)n * 4);
  int*   csr       = (int*)alloc((size_t)e * 4);
  float* pooled    = (float*)alloc(128 * 4);
  u16*   wp        = (u16*)alloc(3 * 2048 * 8 * 2);
  u8*    tmpf8     = (u8*)alloc((size_t)n * 128);
  u16*   houtb     = (u16*)alloc((size_t)n * 128 * 2);
  int*   pairBuf   = (int*)houtb;  // alias: pairs consumed (b_fine) before gather0 writes houtb

  k_init<<<2, 256, 0, stream>>>(ei, mode, bucketCnt, pooled, e, nb);
  b_count<<<192, 256, 0, stream>>>(ei, mode, bucketCnt, e, nb);
  b_bscan<<<1, 256, 0, stream>>>(bucketCnt, bucketOff, bucketCur, nb, e);
  b_scatter<<<(e + SCH - 1) / SCH, 256, 0, stream>>>(ei, mode, bucketCur, pairBuf, e, nb);
  b_fine<<<nb, 512, 0, stream>>>(pairBuf, bucketOff, offs, dis, csr, n, e);

  k_wpack3<<<24, 256, 0, stream>>>(W0, W1, W2, wp);

  int gg = (n + 63) / 64;
  int gn = (n + 3) / 4;

  // layer 0 (reads fp32 x directly)
  k_gemm_mfma<true><<<gg, 256, 0, stream>>>(x, wp, dis, tmpf8, n);
  k_gather_f8<<<gn, 256, 0, stream>>>(tmpf8, csr, offs, dis, b0, houtb, n);
  // layer 1
  k_gemm_mfma<false><<<gg, 256, 0, stream>>>(houtb, wp + 2048 * 8, dis, tmpf8, n);
  k_gather_f8<<<gn, 256, 0, stream>>>(tmpf8, csr, offs, dis, b1, houtb, n);
  // layer 2
  k_gemm_mfma<false><<<gg, 256, 0, stream>>>(houtb, wp + 2 * 2048 * 8, dis, tmpf8, n);
  k_gather_f8<<<gn, 256, 0, stream>>>(tmpf8, csr, offs, dis, b2, houtb, n);

  k_pool_bf<<<512, 256, 0, stream>>>(houtb, pooled, n);
  k_final<<<1, 32, 0, stream>>>(pooled, Wfc, bfc, (float*)d_out, 1.0f / (float)n);
}

// Round 12
// 336.030 us; speedup vs baseline: 1.1032x; 1.1032x over previous
//
#include <hip/hip_runtime.h>
#include <hip/hip_bf16.h>
#include <cstdint>

// ---------------------------------------------------------------------------
// GCN 3-layer forward, bf16 pipeline + MFMA GEMM + fp8 gather operand.
// R12: gather processes 2 nodes per wave over their CONTIGUOUS combined csr
//      range [offs[2i], offs[2i+2]) with one ILP-8 pipeline; scalar compare
//      vs mid=offs[2i+1] routes rows into acc bank A or B. Doubles sustained
//      MLP per wave, halves remainder-tail and fixed costs. (R10/R11 showed
//      gather is latency-bound: fetch -54% => -8%, VALU -30% => -0%.)
//      All other kernels identical to R11.
// ---------------------------------------------------------------------------

typedef unsigned short u16;
typedef unsigned int u32;
typedef unsigned char u8;
typedef __attribute__((ext_vector_type(8))) short short8v;
typedef __attribute__((ext_vector_type(4))) float f32x4;
typedef __attribute__((ext_vector_type(2))) float f32x2;

#define NBMAX 256
#define BKSH  9
#define SCH   2048

__device__ inline u16 f2bf(float f) {
  u32 u = __float_as_uint(f);
  u += 0x7fff + ((u >> 16) & 1);  // RNE
  return (u16)(u >> 16);
}
__device__ inline float bflo(u32 u) { return __uint_as_float(u << 16); }
__device__ inline float bfhi(u32 u) { return __uint_as_float(u & 0xffff0000u); }

// --- init: block 0 detects edge dtype, block 1 zeros counters ---------------
__global__ void k_init(const int* __restrict__ ei, int* __restrict__ mode,
                       int* __restrict__ bucketCnt, float* __restrict__ pooled,
                       int e, int nb) {
  if (blockIdx.x == 0) {
    __shared__ int any;
    if (threadIdx.x == 0) any = 0;
    __syncthreads();
    int lim = min(e, 2048);
    int local = 0;
    for (int i = threadIdx.x; i < lim; i += blockDim.x)
      local |= (ei[2 * i + 1] != 0);
    if (local) atomicOr(&any, 1);
    __syncthreads();
    if (threadIdx.x == 0) mode[0] = (any == 0) ? 1 : 0;
  } else {
    int i = threadIdx.x;
    if (i < nb) bucketCnt[i] = 0;
    if (i < 128) pooled[i] = 0.0f;
  }
}

// --- CSR build: 2-level radix by destination --------------------------------
__global__ __launch_bounds__(256) void b_count(const int* __restrict__ ei,
                                               const int* __restrict__ mode,
                                               int* __restrict__ bucketCnt,
                                               int e, int nb) {
  __shared__ int lh[NBMAX];
  int t = threadIdx.x;
  lh[t] = 0;
  __syncthreads();
  int m = mode[0];
  int stride = gridDim.x * 256;
  for (int i = blockIdx.x * 256 + t; i < e; i += stride) {
    long long di = (long long)e + i;
    int d = m ? ei[2 * di] : ei[di];
    atomicAdd(&lh[d >> BKSH], 1);
  }
  __syncthreads();
  if (t < nb && lh[t]) atomicAdd(&bucketCnt[t], lh[t]);
}

__global__ __launch_bounds__(256) void b_bscan(const int* __restrict__ bucketCnt,
                                               int* __restrict__ bucketOff,
                                               int* __restrict__ bucketCur,
                                               int nb, int e) {
  __shared__ int sh[NBMAX];
  int t = threadIdx.x;
  int c = (t < nb) ? bucketCnt[t] : 0;
  sh[t] = c;
  __syncthreads();
  for (int d = 1; d < NBMAX; d <<= 1) {
    int v = (t >= d) ? sh[t - d] : 0;
    __syncthreads();
    sh[t] += v;
    __syncthreads();
  }
  int ex = sh[t] - c;
  if (t < nb) { bucketOff[t] = ex; bucketCur[t] = ex; }
  if (t == 0) bucketOff[nb] = e;
}

__global__ __launch_bounds__(256) void b_scatter(const int* __restrict__ ei,
                                                 const int* __restrict__ mode,
                                                 int* __restrict__ bucketCur,
                                                 int* __restrict__ pairBuf,
                                                 int e, int nb) {
  __shared__ int cnt[NBMAX];
  __shared__ int pre[NBMAX];
  __shared__ int base[NBMAX];
  __shared__ int stage[2 * SCH];
  const int t = threadIdx.x;
  const int chunk0 = blockIdx.x * SCH;
  const int nloc = min(SCH, e - chunk0);
  const int m = mode[0];

  cnt[t] = 0;
  __syncthreads();

  int myS[SCH / 256], myD[SCH / 256], myB[SCH / 256], mySlot[SCH / 256];
#pragma unroll
  for (int j = 0; j < SCH / 256; ++j) {
    int li = j * 256 + t;
    myB[j] = -1;
    if (li < nloc) {
      int i = chunk0 + li;
      long long di = (long long)e + i;
      int s = m ? ei[2 * (long long)i] : ei[i];
      int d = m ? ei[2 * di] : ei[di];
      int b = d >> BKSH;
      myS[j] = s; myD[j] = d; myB[j] = b;
      mySlot[j] = atomicAdd(&cnt[b], 1);
    }
  }
  __syncthreads();

  int c0 = cnt[t];
  pre[t] = c0;
  __syncthreads();
  for (int d = 1; d < NBMAX; d <<= 1) {
    int v = (t >= d) ? pre[t - d] : 0;
    __syncthreads();
    pre[t] += v;
    __syncthreads();
  }
  int myPre = pre[t] - c0;
  if (t < nb && c0 > 0) base[t] = atomicAdd(&bucketCur[t], c0);
  __syncthreads();
  cnt[t] = myPre;
  __syncthreads();

#pragma unroll
  for (int j = 0; j < SCH / 256; ++j) {
    if (myB[j] >= 0) {
      int si = cnt[myB[j]] + mySlot[j];
      stage[2 * si] = myS[j];
      stage[2 * si + 1] = myD[j];
    }
  }
  __syncthreads();

  int wave = t >> 6, lane = t & 63;
  for (int b = wave; b < nb; b += 4) {
    int cb = pre[b] - cnt[b];
    if (cb <= 0) continue;
    int lo = cnt[b];
    size_t gb = (size_t)base[b];
    for (int j = lane; j < 2 * cb; j += 64)
      pairBuf[2 * gb + j] = stage[2 * lo + j];
  }
}

__global__ __launch_bounds__(512) void b_fine(const int* __restrict__ pairBuf,
                                              const int* __restrict__ bucketOff,
                                              int* __restrict__ offs,
                                              float* __restrict__ dis,
                                              int* __restrict__ csr,
                                              int n, int e) {
  const int b = blockIdx.x;
  const int d0 = b << BKSH;
  const int lo = bucketOff[b], hi = bucketOff[b + 1];
  __shared__ int arr[1 << BKSH];
  __shared__ int cur[1 << BKSH];
  const int t = threadIdx.x;
  arr[t] = 0; cur[t] = 0;
  __syncthreads();
  for (int i = lo + t; i < hi; i += 512) {
    int d = pairBuf[2 * (size_t)i + 1];
    atomicAdd(&arr[d - d0], 1);
  }
  __syncthreads();
  int c0 = arr[t];
  __syncthreads();
  for (int dd = 1; dd < 512; dd <<= 1) {
    int v = (t >= dd) ? arr[t - dd] : 0;
    __syncthreads();
    arr[t] += v;
    __syncthreads();
  }
  int epre = arr[t] - c0;
  int gd = d0 + t;
  if (gd < n) {
    offs[gd] = lo + epre;
    dis[gd] = rsqrtf((float)c0 + 1.0f);
  }
  __syncthreads();
  arr[t] = epre;
  __syncthreads();
  for (int i = lo + t; i < hi; i += 512) {
    int s = pairBuf[2 * (size_t)i];
    int d = pairBuf[2 * (size_t)i + 1];
    int ld = d - d0;
    int p = lo + arr[ld] + atomicAdd(&cur[ld], 1);
    csr[p] = s;
  }
  if (b == 0 && t == 0) offs[n] = e;
}

// --- pack all 3 weights fp32 -> MFMA B-fragments bf16 (grid 24) -------------
__global__ __launch_bounds__(256) void k_wpack3(const float* __restrict__ W0,
                                                const float* __restrict__ W1,
                                                const float* __restrict__ W2,
                                                u16* __restrict__ wp) {
  int f = blockIdx.x * 256 + threadIdx.x;
  int wsel = f >> 11;
  int li = f & 2047;
  const float* W = (wsel == 0) ? W0 : (wsel == 1) ? W1 : W2;
  u16* dst = wp + (size_t)wsel * 2048 * 8;
  int ct = li >> 8, kc = (li >> 6) & 3, lane = li & 63;
  int g = lane >> 4, c = lane & 15;
  u32 o[4];
#pragma unroll
  for (int q = 0; q < 4; ++q) {
    int k = kc * 32 + g * 8 + q * 2;
    u16 e0 = f2bf(W[(size_t)k * 128 + ct * 16 + c]);
    u16 e1 = f2bf(W[(size_t)(k + 1) * 128 + ct * 16 + c]);
    o[q] = (u32)e0 | ((u32)e1 << 16);
  }
  uint4 v; v.x = o[0]; v.y = o[1]; v.z = o[2]; v.w = o[3];
  *reinterpret_cast<uint4*>(dst + (size_t)li * 8) = v;
}

// --- GEMM: tmp[r,:] = fp8( 16 * dis[r] * (h[r,:] @ W) ) via MFMA ------------
template <bool FP32IN>
__global__ __launch_bounds__(256) void k_gemm_mfma(const void* __restrict__ hin,
                                                   const u16* __restrict__ wp,
                                                   const float* __restrict__ dis,
                                                   u8* __restrict__ tmpf8, int n) {
  __shared__ float eps[64 * 132];
  const int tid = threadIdx.x;
  const int w = tid >> 6, l = tid & 63;
  const int g = l >> 4, c16 = l & 15;
  const int rowbase = blockIdx.x * 64 + w * 16;

  const short8v zero8 = {0, 0, 0, 0, 0, 0, 0, 0};
  short8v a[4];
  int ar = rowbase + c16;
  bool aok = ar < n;
#pragma unroll
  for (int kc = 0; kc < 4; ++kc) {
    if (FP32IN) {
      const float* hrow = (const float*)hin + (size_t)ar * 128;
      short8v s = zero8;
      if (aok) {
        float4 v0 = *reinterpret_cast<const float4*>(hrow + kc * 32 + g * 8);
        float4 v1 = *reinterpret_cast<const float4*>(hrow + kc * 32 + g * 8 + 4);
        s[0] = (short)f2bf(v0.x); s[1] = (short)f2bf(v0.y);
        s[2] = (short)f2bf(v0.z); s[3] = (short)f2bf(v0.w);
        s[4] = (short)f2bf(v1.x); s[5] = (short)f2bf(v1.y);
        s[6] = (short)f2bf(v1.z); s[7] = (short)f2bf(v1.w);
      }
      a[kc] = s;
    } else {
      const u16* hrow = (const u16*)hin + (size_t)ar * 128;
      a[kc] = aok ? *reinterpret_cast<const short8v*>(hrow + kc * 32 + g * 8) : zero8;
    }
  }

  f32x4 acc[8];
#pragma unroll
  for (int ct = 0; ct < 8; ++ct) acc[ct] = f32x4{0.f, 0.f, 0.f, 0.f};

#pragma unroll
  for (int ct = 0; ct < 8; ++ct) {
#pragma unroll
    for (int kc = 0; kc < 4; ++kc) {
      short8v b = *reinterpret_cast<const short8v*>(wp + ((size_t)(ct * 4 + kc) * 64 + l) * 8);
      acc[ct] = __builtin_amdgcn_mfma_f32_16x16x32_bf16(a[kc], b, acc[ct], 0, 0, 0);
    }
  }

  // scale by 16*dis[row] (x16 clears fp8 subnormal region; gather divides out)
#pragma unroll
  for (int j = 0; j < 4; ++j) {
    int rl = w * 16 + g * 4 + j;
    int gr = blockIdx.x * 64 + rl;
    float dn = (gr < n) ? dis[gr] * 16.0f : 0.f;
#pragma unroll
    for (int ct = 0; ct < 8; ++ct)
      eps[rl * 132 + ct * 16 + c16] = acc[ct][j] * dn;
  }
  __syncthreads();

  // readback: thread -> (row rl, 32-col segment), pack fp8 and store 32B
  int rl = tid >> 2, seg = tid & 3;
  int gr = blockIdx.x * 64 + rl;
  if (gr < n) {
    const float* src = &eps[rl * 132 + seg * 32];
    u32 wds[8];
#pragma unroll
    for (int q = 0; q < 4; ++q) {
      float4 v0 = *reinterpret_cast<const float4*>(src + q * 8);
      float4 v1 = *reinterpret_cast<const float4*>(src + q * 8 + 4);
      int p0 = __builtin_amdgcn_cvt_pk_fp8_f32(v0.x, v0.y, 0, false);
      p0 = __builtin_amdgcn_cvt_pk_fp8_f32(v0.z, v0.w, p0, true);
      int p1 = __builtin_amdgcn_cvt_pk_fp8_f32(v1.x, v1.y, 0, false);
      p1 = __builtin_amdgcn_cvt_pk_fp8_f32(v1.z, v1.w, p1, true);
      wds[q * 2] = (u32)p0;
      wds[q * 2 + 1] = (u32)p1;
    }
    uint4 o0; o0.x = wds[0]; o0.y = wds[1]; o0.z = wds[2]; o0.w = wds[3];
    uint4 o1; o1.x = wds[4]; o1.y = wds[5]; o1.z = wds[6]; o1.w = wds[7];
    *reinterpret_cast<uint4*>(tmpf8 + (size_t)gr * 128 + seg * 32) = o0;
    *reinterpret_cast<uint4*>(tmpf8 + (size_t)gr * 128 + seg * 32 + 16) = o1;
  }
}

// --- gather: 2 nodes per wave over the contiguous combined csr range --------
// nodes (2i,2i+1) share range [offs[2i], offs[2i+2]); one ILP-8 pipeline,
// scalar compare vs mid routes into acc bank A/B. Scalar row offsets via
// readfirstlane; per-lane base hoisted; packed fp8->f32x2 convert.
__global__ __launch_bounds__(256) void k_gather_f8(const u8* __restrict__ tmpf8,
                                                   const int* __restrict__ csr,
                                                   const int* __restrict__ offs,
                                                   const float* __restrict__ dis,
                                                   const float* __restrict__ bias,
                                                   u16* __restrict__ houtb, int n) {
  int node0 = blockIdx.x * 8 + (threadIdx.x >> 6) * 2;
  if (node0 >= n) return;
  int node1 = node0 + 1;
  bool has1 = node1 < n;
  int lane = threadIdx.x & 63;
  const u16* tp = reinterpret_cast<const u16*>(tmpf8) + lane;  // per-lane base

  int s0  = __builtin_amdgcn_readfirstlane(offs[node0]);
  int mid = __builtin_amdgcn_readfirstlane(offs[node1]);
  int s1  = has1 ? __builtin_amdgcn_readfirstlane(offs[node1 + 1]) : mid;

  f32x2 accA[4], accB[4];
#pragma unroll
  for (int i = 0; i < 4; ++i) { accA[i] = f32x2{0.f, 0.f}; accB[i] = f32x2{0.f, 0.f}; }

  // self-loop rows (issued first, latency overlaps the loop)
  accA[1] += __builtin_amdgcn_cvt_pk_f32_fp8((int)tp[(u32)node0 << 6], false);
  if (has1)
    accB[1] += __builtin_amdgcn_cvt_pk_f32_fp8((int)tp[(u32)node1 << 6], false);

  int e = s0;
  for (; e + 7 < s1; e += 8) {
    int ro[8];
#pragma unroll
    for (int j = 0; j < 8; ++j)
      ro[j] = __builtin_amdgcn_readfirstlane(csr[e + j]) << 6;  // u16 elems
    u32 v[8];
#pragma unroll
    for (int j = 0; j < 8; ++j) v[j] = tp[(u32)ro[j]];
#pragma unroll
    for (int j = 0; j < 8; ++j) {
      f32x2 f = __builtin_amdgcn_cvt_pk_f32_fp8((int)v[j], false);
      if (e + j < mid) accA[j & 3] += f; else accB[j & 3] += f;
    }
  }
  for (; e < s1; ++e) {
    int r = __builtin_amdgcn_readfirstlane(csr[e]) << 6;
    f32x2 f = __builtin_amdgcn_cvt_pk_f32_fp8((int)tp[(u32)r], false);
    if (e < mid) accA[0] += f; else accB[0] += f;
  }

  float2 bb = reinterpret_cast<const float2*>(bias)[lane];
  {
    f32x2 s = (accA[0] + accA[1]) + (accA[2] + accA[3]);
    float dn = dis[node0] * 0.0625f;
    float rx = fmaf(dn, s.x, bb.x);
    float ry = fmaf(dn, s.y, bb.y);
    rx = rx > 0.f ? rx : 0.f;
    ry = ry > 0.f ? ry : 0.f;
    u32 o = (u32)f2bf(rx) | ((u32)f2bf(ry) << 16);
    reinterpret_cast<u32*>(houtb)[(size_t)node0 * 64 + lane] = o;
  }
  if (has1) {
    f32x2 s = (accB[0] + accB[1]) + (accB[2] + accB[3]);
    float dn = dis[node1] * 0.0625f;
    float rx = fmaf(dn, s.x, bb.x);
    float ry = fmaf(dn, s.y, bb.y);
    rx = rx > 0.f ? rx : 0.f;
    ry = ry > 0.f ? ry : 0.f;
    u32 o = (u32)f2bf(rx) | ((u32)f2bf(ry) << 16);
    reinterpret_cast<u32*>(houtb)[(size_t)node1 * 64 + lane] = o;
  }
}

// --- mean-pool column sums (bf16 in, fp32 out); 512 blocks -> 65K atomics ---
__global__ __launch_bounds__(256) void k_pool_bf(const u16* __restrict__ h,
                                                 float* __restrict__ pooled, int n) {
  int lane = threadIdx.x & 63, wv = threadIdx.x >> 6;
  const u32* hp = reinterpret_cast<const u32*>(h);
  float sx = 0.f, sy = 0.f;
  for (int r = blockIdx.x * 4 + wv; r < n; r += gridDim.x * 4) {
    u32 u = hp[(size_t)r * 64 + lane];
    sx += bflo(u); sy += bfhi(u);
  }
  __shared__ float red[2][256];
  red[0][threadIdx.x] = sx;
  red[1][threadIdx.x] = sy;
  __syncthreads();
  if (threadIdx.x < 64) {
    float tx = red[0][threadIdx.x] + red[0][threadIdx.x + 64] +
               red[0][threadIdx.x + 128] + red[0][threadIdx.x + 192];
    float ty = red[1][threadIdx.x] + red[1][threadIdx.x + 64] +
               red[1][threadIdx.x + 128] + red[1][threadIdx.x + 192];
    atomicAdd(&pooled[threadIdx.x * 2], tx);
    atomicAdd(&pooled[threadIdx.x * 2 + 1], ty);
  }
}

__global__ void k_final(const float* __restrict__ pooled, const float* __restrict__ Wfc,
                        const float* __restrict__ bfc, float* __restrict__ out,
                        float invn) {
  int j = threadIdx.x;
  if (j < 32) {
    float acc = 0.f;
    for (int k = 0; k < 128; ++k) acc = fmaf(pooled[k], Wfc[k * 32 + j], acc);
    out[j] = fmaf(acc, invn, bfc[j]);
  }
}

extern "C" void kernel_launch(void* const* d_in, const int* in_sizes, int n_in,
                              void* d_out, int out_size, void* d_ws, size_t ws_size,
                              hipStream_t stream) {
  const float* x   = (const float*)d_in[0];
  const int*   ei  = (const int*)d_in[1];
  const float* W0  = (const float*)d_in[2];
  const float* b0  = (const float*)d_in[3];
  const float* W1  = (const float*)d_in[4];
  const float* b1  = (const float*)d_in[5];
  const float* W2  = (const float*)d_in[6];
  const float* b2  = (const float*)d_in[7];
  const float* Wfc = (const float*)d_in[8];
  const float* bfc = (const float*)d_in[9];

  const int n = in_sizes[0] / 128;
  const int e = in_sizes[1] / 2;
  const int nb = (n + (1 << BKSH) - 1) >> BKSH;

  char* ws = (char*)d_ws;
  size_t off = 0;
  auto alloc = [&](size_t bytes) -> void* {
    void* p = ws + off;
    off = (off + bytes + 255) & ~(size_t)255;
    return p;
  };
  int*   mode      = (int*)alloc(sizeof(int));
  int*   bucketCnt = (int*)alloc(NBMAX * 4);
  int*   bucketOff = (int*)alloc((NBMAX + 1) * 4);
  int*   bucketCur = (int*)alloc(NBMAX * 4);
  int*   offs      = (int*)alloc((size_t)(n + 1) * 4);
  float* dis       = (float*)alloc((size_t)n * 4);
  int*   csr       = (int*)alloc((size_t)e * 4);
  float* pooled    = (float*)alloc(128 * 4);
  u16*   wp        = (u16*)alloc(3 * 2048 * 8 * 2);
  u8*    tmpf8     = (u8*)alloc((size_t)n * 128);
  u16*   houtb     = (u16*)alloc((size_t)n * 128 * 2);
  int*   pairBuf   = (int*)houtb;  // alias: pairs consumed (b_fine) before gather0 writes houtb

  k_init<<<2, 256, 0, stream>>>(ei, mode, bucketCnt, pooled, e, nb);
  b_count<<<192, 256, 0, stream>>>(ei, mode, bucketCnt, e, nb);
  b_bscan<<<1, 256, 0, stream>>>(bucketCnt, bucketOff, bucketCur, nb, e);
  b_scatter<<<(e + SCH - 1) / SCH, 256, 0, stream>>>(ei, mode, bucketCur, pairBuf, e, nb);
  b_fine<<<nb, 512, 0, stream>>>(pairBuf, bucketOff, offs, dis, csr, n, e);

  k_wpack3<<<24, 256, 0, stream>>>(W0, W1, W2, wp);

  int gg = (n + 63) / 64;
  int gn = (n + 7) / 8;

  // layer 0 (reads fp32 x directly)
  k_gemm_mfma<true><<<gg, 256, 0, stream>>>(x, wp, dis, tmpf8, n);
  k_gather_f8<<<gn, 256, 0, stream>>>(tmpf8, csr, offs, dis, b0, houtb, n);
  // layer 1
  k_gemm_mfma<false><<<gg, 256, 0, stream>>>(houtb, wp + 2048 * 8, dis, tmpf8, n);
  k_gather_f8<<<gn, 256, 0, stream>>>(tmpf8, csr, offs, dis, b1, houtb, n);
  // layer 2
  k_gemm_mfma<false><<<gg, 256, 0, stream>>>(houtb, wp + 2 * 2048 * 8, dis, tmpf8, n);
  k_gather_f8<<<gn, 256, 0, stream>>>(tmpf8, csr, offs, dis, b2, houtb, n);

  k_pool_bf<<<512, 256, 0, stream>>>(houtb, pooled, n);
  k_final<<<1, 32, 0, stream>>>(pooled, Wfc, bfc, (float*)d_out, 1.0f / (float)n);
}